// Round 11
// baseline (1069.298 us; speedup 1.0000x reference)
//
#include <hip/hip_runtime.h>
#include <math.h>

// CapsuleLayer routing on MI355X (gfx950). fp32 in/out.
// B=64, n=2048, k=32, in_C=16, out_C=32, 3 routing iterations.
//
// Round-11: fused passes, barrier-exposure fix. Rounds 9/10 both sat at
// ~110 us with 1 block/CU and 2 block-wide barriers per node (occ 41%,
// VALU 20%): when the single resident block stalls at __syncthreads the CU
// idles. Changes: (1) PNB 16->8 => 512 blocks = 2 blocks/CU; (2) ONE
// barrier/node: waves write per-b exp-partials to private slots
// esum[b][wave] (no atomics/zeroing; 16 waves x 32 b covers all slots),
// barrier, lanes row-sum 16 via 4x ds_read_b128; probs computed in-register
// from the wave's own e and c (no probs LDS round-trip, no remap phase);
// (3) logits layout [n][k][b] (128B-coalesced, prefetchable).

#define BATCH 64
#define NN    2048
#define NK    32
#define NI    16
#define NO    32

#define PNB   8                   // nodes per fused block
#define NSETS (NN / PNB)          // 256 node-sets
#define ESTR  20                  // esum row stride (floats): 16B-aligned rows

typedef __bf16 bf16x8 __attribute__((ext_vector_type(8)));
typedef float  f32x16 __attribute__((ext_vector_type(16)));

__device__ __forceinline__ unsigned short f2bf(float f) {
    unsigned int x = __float_as_uint(f);
    unsigned int lsb = (x >> 16) & 1u;
    x += 0x7fffu + lsb;                 // RNE
    return (unsigned short)(x >> 16);
}
__device__ __forceinline__ float bflo(unsigned int u) { return __uint_as_float(u << 16); }
__device__ __forceinline__ float bfhi(unsigned int u) { return __uint_as_float(u & 0xffff0000u); }

// ---------------- fast path ----------------

__global__ __launch_bounds__(1024) void zero_kernel(float* __restrict__ p) {
    p[blockIdx.x * 1024 + threadIdx.x] = 0.f;
}

// x [b][n][i] fp32 -> xT [n][b][i] bf16
__global__ __launch_bounds__(256) void xt_kernel(const float* __restrict__ xg,
                                                 unsigned short* __restrict__ xT) {
    int id = blockIdx.x * 256 + threadIdx.x;      // 524288
    int b = id >> 13;
    int rem = id & 8191;
    int n = rem >> 2;
    int i4 = rem & 3;
    float4 v = *(const float4*)(xg + ((size_t)b * NN + n) * NI + i4 * 4);
    ushort4 o;
    o.x = f2bf(v.x); o.y = f2bf(v.y); o.z = f2bf(v.z); o.w = f2bf(v.w);
    *(ushort4*)(xT + ((size_t)n * BATCH + b) * NI + i4 * 4) = o;
}

// W fp32 [n][k][i][o] -> wq bf16 [n][k][o][i] (A-fragment-ready).
__global__ __launch_bounds__(256) void wqt_kernel(const float* __restrict__ Wg,
                                                  unsigned short* __restrict__ wq) {
    const int w    = threadIdx.x >> 6;
    const int lane = threadIdx.x & 63;
    const int task = blockIdx.x * 4 + w;          // 65536 = n*32 + k
    const int o  = lane & 31;
    const int ih = lane >> 5;                     // i-half
    const float* src = Wg + (size_t)task * (NI * NO);
    unsigned short d[8];
#pragma unroll
    for (int j = 0; j < 8; ++j)
        d[j] = f2bf(src[(ih * 8 + j) * NO + o]);
    *(uint4*)(wq + (size_t)task * (NO * NI) + o * NI + ih * 8) = *(uint4*)d;
}

// Fused routing pass. Grid (256 sets, 2 b-halves), block 1024 = 16 waves.
// Wave w owns k0=2w, k1=2w+1. MFMA: A=wq[k][o][i] (rows o), B=xT[b][i]
// (cols b) -> D[row o=(r&3)+8*(r>>2)+4*h5][col b=l5] (round-5/10 verified).
// Per node (PASS>=1): mfma x2 -> in-reg delta dot + shfl_xor(32) -> exp ->
// h5==0 lanes store e0+e1 to esum[buf][b][w] -> ONE barrier -> lanes
// row-sum 16 partials (4x ds_read_b128) -> p = e*inv in-reg -> accumulate.
// PASS 0: pure MFMA accumulate, no LDS/barriers. End: atomicAdd s_glob.
template <int PASS>
__global__ __launch_bounds__(1024) void fused_pass(
    const unsigned short* __restrict__ xT,   // bf16 [n][b][i]
    const unsigned short* __restrict__ wq,   // bf16 [n][k][o][i]
    const float* __restrict__ outv,          // fp32 [k][o][b]   (PASS>=1)
    float* __restrict__ logits0,             // fp32 [n][k][b]   (PASS>=1)
    float* __restrict__ s_glob)              // fp32 [k][o][b], pre-zeroed
{
    __shared__ float esum[2][32 * ESTR];         // 5120 B

    const int tid  = threadIdx.x;
    const int w    = tid >> 6;                   // 0..15
    const int lane = tid & 63;
    const int l5   = lane & 31;                  // b (local) = MFMA col
    const int h5   = lane >> 5;                  // o-half
    const int set  = blockIdx.x;
    const int hb   = blockIdx.y;
    const int k0   = 2 * w, k1 = 2 * w + 1;
    const int gb5  = hb * 32 + l5;               // global b for this lane
    const int nbase = set * PNB;

    // out fragments, packed bf16 pairs (regs r, r+1)
    unsigned orp0[8], orp1[8];
    if constexpr (PASS >= 1) {
#pragma unroll
        for (int q = 0; q < 8; ++q) {
            const int oA = ((2*q) & 3) + 8 * ((2*q) >> 2) + 4 * h5;
            const int oB = ((2*q+1) & 3) + 8 * ((2*q+1) >> 2) + 4 * h5;
            float a0 = outv[(k0 * NO + oA) * BATCH + gb5];
            float b0 = outv[(k0 * NO + oB) * BATCH + gb5];
            float a1 = outv[(k1 * NO + oA) * BATCH + gb5];
            float b1 = outv[(k1 * NO + oB) * BATCH + gb5];
            orp0[q] = (unsigned)f2bf(a0) | ((unsigned)f2bf(b0) << 16);
            orp1[q] = (unsigned)f2bf(a1) | ((unsigned)f2bf(b1) << 16);
        }
    }

    float sa0[16], sa1[16];
#pragma unroll
    for (int r = 0; r < 16; ++r) { sa0[r] = 0.f; sa1[r] = 0.f; }

    // depth-1 prefetch
    bf16x8 aN, b0N, b1N;
    float gN0 = 0.f, gN1 = 0.f;
    {
        const int n = nbase;
        b0N = *(const bf16x8*)(wq + (size_t)n * (NK * NO * NI) + k0 * (NO * NI) + l5 * NI + h5 * 8);
        b1N = *(const bf16x8*)(wq + (size_t)n * (NK * NO * NI) + k1 * (NO * NI) + l5 * NI + h5 * 8);
        aN  = *(const bf16x8*)(xT + (size_t)n * (BATCH * NI) + gb5 * NI + h5 * 8);
        if constexpr (PASS == 2) {
            gN0 = logits0[(size_t)n * (NK * BATCH) + k0 * BATCH + gb5];
            gN1 = logits0[(size_t)n * (NK * BATCH) + k1 * BATCH + gb5];
        }
    }

    int buf = 0;
    for (int j = 0; j < PNB; ++j) {
        const int n = nbase + j;
        const bf16x8 aC = aN, b0C = b0N, b1C = b1N;
        const float gC0 = gN0, gC1 = gN1;
        if (j < PNB - 1) {
            const int n2 = n + 1;
            b0N = *(const bf16x8*)(wq + (size_t)n2 * (NK * NO * NI) + k0 * (NO * NI) + l5 * NI + h5 * 8);
            b1N = *(const bf16x8*)(wq + (size_t)n2 * (NK * NO * NI) + k1 * (NO * NI) + l5 * NI + h5 * 8);
            aN  = *(const bf16x8*)(xT + (size_t)n2 * (BATCH * NI) + gb5 * NI + h5 * 8);
            if constexpr (PASS == 2) {
                gN0 = logits0[(size_t)n2 * (NK * BATCH) + k0 * BATCH + gb5];
                gN1 = logits0[(size_t)n2 * (NK * BATCH) + k1 * BATCH + gb5];
            }
        }

        f32x16 c0, c1;
#pragma unroll
        for (int r = 0; r < 16; ++r) { c0[r] = 0.f; c1[r] = 0.f; }
        c0 = __builtin_amdgcn_mfma_f32_32x32x16_bf16(b0C, aC, c0, 0, 0, 0);  // A=wq(k0), B=x
        c1 = __builtin_amdgcn_mfma_f32_32x32x16_bf16(b1C, aC, c1, 0, 0, 0);  // A=wq(k1), B=x

        if constexpr (PASS == 0) {
#pragma unroll
            for (int r = 0; r < 16; ++r) { sa0[r] += c0[r]; sa1[r] += c1[r]; }
        } else {
            // delta dot over this lane's o-half, then cross-half sum
            float d0 = 0.f, d1 = 0.f;
#pragma unroll
            for (int r = 0; r < 16; ++r) {
                const unsigned u0 = orp0[r >> 1], u1 = orp1[r >> 1];
                const float o0 = (r & 1) ? bfhi(u0) : bflo(u0);
                const float o1 = (r & 1) ? bfhi(u1) : bflo(u1);
                d0 = fmaf(c0[r], o0, d0);
                d1 = fmaf(c1[r], o1, d1);
            }
            d0 += __shfl_xor(d0, 32);
            d1 += __shfl_xor(d1, 32);

            float l0, l1;
            if constexpr (PASS == 1) {
                l0 = d0; l1 = d1;
                if (h5 == 0) {
                    logits0[(size_t)n * (NK * BATCH) + k0 * BATCH + gb5] = d0;  // 128B runs
                    logits0[(size_t)n * (NK * BATCH) + k1 * BATCH + gb5] = d1;
                }
            } else {
                l0 = gC0 + d0;
                l1 = gC1 + d1;
            }
            // no max-subtraction: |l| <= ~8, fp32-safe (rounds 7-10 verified)
            const float e0 = __expf(l0), e1 = __expf(l1);
            if (h5 == 0)
                esum[buf][l5 * ESTR + w] = e0 + e1;      // private slot, no race
            __syncthreads();

            const float4* er = (const float4*)&esum[buf][l5 * ESTR];
            float4 A = er[0], B = er[1], C = er[2], D = er[3];
            const float es = ((A.x + A.y) + (A.z + A.w)) + ((B.x + B.y) + (B.z + B.w))
                           + ((C.x + C.y) + (C.z + C.w)) + ((D.x + D.y) + (D.z + D.w));
            const float inv = __fdividef(1.f, es);
            const float p0 = e0 * inv, p1 = e1 * inv;
#pragma unroll
            for (int r = 0; r < 16; ++r) {
                sa0[r] = fmaf(p0, c0[r], sa0[r]);
                sa1[r] = fmaf(p1, c1[r], sa1[r]);
            }
            buf ^= 1;
        }
    }

    const float scale = (PASS == 0) ? (1.f / NK) : 1.f;
#pragma unroll
    for (int r = 0; r < 16; ++r) {
        const int o = (r & 3) + 8 * (r >> 2) + 4 * h5;
        atomicAdd(&s_glob[(k0 * NO + o) * BATCH + gb5], sa0[r] * scale);
        atomicAdd(&s_glob[(k1 * NO + o) * BATCH + gb5], sa1[r] * scale);
    }
}

// Squash s_glob[k][o][b] -> outv [k][o][b] (or final outp [b][1][k][o]);
// re-zeros s_glob for the next pass. Grid 32 (one block per k).
template <int FINAL>
__global__ __launch_bounds__(1024) void reduce_squash2(
    float* __restrict__ s_glob,
    float* __restrict__ outv,
    float* __restrict__ outp)
{
    __shared__ float red[2048];
    __shared__ float coef[64];
    const int k = blockIdx.x;
    const int t = threadIdx.x;
    const int o = t >> 6;          // 0..15
    const int b = t & 63;
    float* base = s_glob + k * 2048;
    float va = base[o * 64 + b];
    float vb = base[(o + 16) * 64 + b];
    base[o * 64 + b] = 0.f;
    base[(o + 16) * 64 + b] = 0.f;
    red[o * 64 + b] = va * va;
    red[(o + 16) * 64 + b] = vb * vb;
    __syncthreads();
    if (t < 64) {
        float sq = 0.f;
#pragma unroll
        for (int oo = 0; oo < 32; ++oo) sq += red[oo * 64 + t];
        coef[t] = sq / ((1.f + sq) * sqrtf(sq));
    }
    __syncthreads();
    const float cf = coef[b];
    if (FINAL) {
        outp[b * 1024 + k * 32 + o]      = va * cf;
        outp[b * 1024 + k * 32 + o + 16] = vb * cf;
    } else {
        outv[k * 2048 + o * 64 + b]        = va * cf;
        outv[k * 2048 + (o + 16) * 64 + b] = vb * cf;
    }
}

// ---------------- legacy fallback (round-2 code, known-good 582 us) ----------------

#define LBB 32
#define LNCHUNK 8
#define LNBLK (NN / LNCHUNK)
#define LTHREADS 512
#define WK_STRIDE 516

template <int PASS>
__global__ __launch_bounds__(LTHREADS, 1) void legacy_pass(
    const float* __restrict__ xg, const float* __restrict__ Wg,
    const float* __restrict__ outvL, float* __restrict__ logits,
    float* __restrict__ partial)
{
    __shared__ float w_lds[NK * WK_STRIDE];
    __shared__ float x_lds[LBB][NI + 1];
    __shared__ float delta_lds[LBB][NK + 1];
    const int t = threadIdx.x, nb = blockIdx.x, bg = blockIdx.y;
    const int b0 = bg * LBB;
    const int k = t >> 4, bq = t & 15, bl0 = bq * 2, bl1 = bq * 2 + 1;
    float acc0[NO], acc1[NO];
#pragma unroll
    for (int o = 0; o < NO; ++o) { acc0[o] = 0.f; acc1[o] = 0.f; }
    float outr0[NO], outr1[NO];
    if constexpr (PASS >= 1) {
        const float4* o0 = (const float4*)&outvL[((b0 + bl0) * NK + k) * NO];
        const float4* o1 = (const float4*)&outvL[((b0 + bl1) * NK + k) * NO];
#pragma unroll
        for (int q = 0; q < NO / 4; ++q) {
            float4 a = o0[q]; float4 b = o1[q];
            outr0[4*q+0]=a.x; outr0[4*q+1]=a.y; outr0[4*q+2]=a.z; outr0[4*q+3]=a.w;
            outr1[4*q+0]=b.x; outr1[4*q+1]=b.y; outr1[4*q+2]=b.z; outr1[4*q+3]=b.w;
        }
    }
    for (int j = 0; j < LNCHUNK; ++j) {
        const int n = nb * LNCHUNK + j;
        __syncthreads();
        {
            const float4* src = (const float4*)(Wg + (size_t)n * (NK * NI * NO));
#pragma unroll
            for (int r = 0; r < (NK * NI * NO / 4) / LTHREADS; ++r) {
                int idx4 = t + r * LTHREADS;
                float4 v = src[idx4];
                int e = idx4 * 4, kk = e >> 9, rem = e & 511;
                *(float4*)&w_lds[kk * WK_STRIDE + rem] = v;
            }
        }
        { int bl = t >> 4, i = t & 15;
          x_lds[bl][i] = xg[((size_t)(b0 + bl) * NN + n) * NI + i]; }
        __syncthreads();
        if constexpr (PASS == 0) {
#pragma unroll
            for (int i = 0; i < NI; ++i) {
                float xa = x_lds[bl0][i], xb = x_lds[bl1][i];
                const float* wrow = &w_lds[k * WK_STRIDE + i * NO];
#pragma unroll
                for (int o = 0; o < NO; ++o) {
                    float w = wrow[o];
                    acc0[o] = fmaf(xa, w, acc0[o]);
                    acc1[o] = fmaf(xb, w, acc1[o]);
                }
            }
        } else {
            float pr0[NO], pr1[NO];
#pragma unroll
            for (int o = 0; o < NO; ++o) { pr0[o] = 0.f; pr1[o] = 0.f; }
#pragma unroll
            for (int i = 0; i < NI; ++i) {
                float xa = x_lds[bl0][i], xb = x_lds[bl1][i];
                const float* wrow = &w_lds[k * WK_STRIDE + i * NO];
#pragma unroll
                for (int o = 0; o < NO; ++o) {
                    float w = wrow[o];
                    pr0[o] = fmaf(xa, w, pr0[o]);
                    pr1[o] = fmaf(xb, w, pr1[o]);
                }
            }
            float d0 = 0.f, d1 = 0.f;
#pragma unroll
            for (int o = 0; o < NO; ++o) {
                d0 = fmaf(pr0[o], outr0[o], d0);
                d1 = fmaf(pr1[o], outr1[o], d1);
            }
            float l0 = d0, l1 = d1;
            const size_t li0 = ((size_t)(b0 + bl0) * NN + n) * NK + k;
            const size_t li1 = ((size_t)(b0 + bl1) * NN + n) * NK + k;
            if constexpr (PASS == 2) { l0 += logits[li0]; l1 += logits[li1]; }
            else { logits[li0] = d0; logits[li1] = d1; }
            delta_lds[bl0][k] = l0; delta_lds[bl1][k] = l1;
            __syncthreads();
            float m0 = -1e30f, m1 = -1e30f;
#pragma unroll
            for (int kk = 0; kk < NK; ++kk) {
                m0 = fmaxf(m0, delta_lds[bl0][kk]);
                m1 = fmaxf(m1, delta_lds[bl1][kk]);
            }
            float s0 = 0.f, s1 = 0.f;
#pragma unroll
            for (int kk = 0; kk < NK; ++kk) {
                s0 += __expf(delta_lds[bl0][kk] - m0);
                s1 += __expf(delta_lds[bl1][kk] - m1);
            }
            float p0 = __expf(l0 - m0) / s0;
            float p1 = __expf(l1 - m1) / s1;
#pragma unroll
            for (int o = 0; o < NO; ++o) {
                acc0[o] = fmaf(p0, pr0[o], acc0[o]);
                acc1[o] = fmaf(p1, pr1[o], acc1[o]);
            }
        }
    }
    const float scale = (PASS == 0) ? (1.f / NK) : 1.f;
    float4* p0 = (float4*)&partial[(((size_t)nb * BATCH + (b0 + bl0)) * NK + k) * NO];
    float4* p1 = (float4*)&partial[(((size_t)nb * BATCH + (b0 + bl1)) * NK + k) * NO];
#pragma unroll
    for (int q = 0; q < NO / 4; ++q) {
        float4 v0, v1;
        v0.x = acc0[4*q+0]*scale; v0.y = acc0[4*q+1]*scale;
        v0.z = acc0[4*q+2]*scale; v0.w = acc0[4*q+3]*scale;
        v1.x = acc1[4*q+0]*scale; v1.y = acc1[4*q+1]*scale;
        v1.z = acc1[4*q+2]*scale; v1.w = acc1[4*q+3]*scale;
        p0[q] = v0; p1[q] = v1;
    }
}

__global__ __launch_bounds__(256) void legacy_reduce(
    const float* __restrict__ partial, float* __restrict__ outf)
{
    const int tid = blockIdx.x * 256 + threadIdx.x;
    float v = 0.f;
    for (int nb = 0; nb < LNBLK; ++nb)
        v += partial[(size_t)nb * (BATCH * NK * NO) + tid];
    float sq = v * v;
#pragma unroll
    for (int off = 1; off < 32; off <<= 1) sq += __shfl_xor(sq, off);
    float coef = sq / ((1.f + sq) * sqrtf(sq));
    outf[tid] = v * coef;
}

// ---------------- launch ----------------

extern "C" void kernel_launch(void* const* d_in, const int* in_sizes, int n_in,
                              void* d_out, int out_size, void* d_ws, size_t ws_size,
                              hipStream_t stream)
{
    const float* xg = (const float*)d_in[0];
    const float* Wg = (const float*)d_in[1];
    float* outp = (float*)d_out;
    char* ws = (char*)d_ws;

    const size_t SZ_WQ     = (size_t)NN * NK * NO * NI * 2;          //  64 MiB
    const size_t SZ_XT     = (size_t)NN * BATCH * NI * 2;            //   4 MiB
    const size_t SZ_LOGITS = (size_t)NN * NK * BATCH * 4;            //  16 MiB
    const size_t SZ_SG     = (size_t)NK * NO * BATCH * 4;            // 256 KiB
    const size_t SZ_OUTV   = (size_t)NK * NO * BATCH * 4;            // 256 KiB
    const size_t NEED = SZ_WQ + SZ_XT + SZ_LOGITS + SZ_SG + SZ_OUTV;

    if (ws_size >= NEED) {
        unsigned short* wq = (unsigned short*)ws;
        unsigned short* xT = (unsigned short*)(ws + SZ_WQ);
        float* logits0 = (float*)(ws + SZ_WQ + SZ_XT);
        float* s_glob  = (float*)(ws + SZ_WQ + SZ_XT + SZ_LOGITS);
        float* outv    = (float*)(ws + SZ_WQ + SZ_XT + SZ_LOGITS + SZ_SG);

        zero_kernel<<<64, 1024, 0, stream>>>(s_glob);
        xt_kernel<<<2048, 256, 0, stream>>>(xg, xT);
        wqt_kernel<<<16384, 256, 0, stream>>>(Wg, wq);

        dim3 pg(NSETS, 2);   // 512 blocks = 2 blocks/CU
        fused_pass<0><<<pg, 1024, 0, stream>>>(xT, wq, nullptr, nullptr, s_glob);
        reduce_squash2<0><<<32, 1024, 0, stream>>>(s_glob, outv, nullptr);
        fused_pass<1><<<pg, 1024, 0, stream>>>(xT, wq, outv, logits0, s_glob);
        reduce_squash2<0><<<32, 1024, 0, stream>>>(s_glob, outv, nullptr);
        fused_pass<2><<<pg, 1024, 0, stream>>>(xT, wq, outv, logits0, s_glob);
        reduce_squash2<1><<<32, 1024, 0, stream>>>(s_glob, nullptr, outp);
    } else {
        float* partial = (float*)ws;
        float* logits = (float*)(ws + (size_t)LNBLK * BATCH * NK * NO * 4);
        float* outvL = (float*)(ws + (size_t)LNBLK * BATCH * NK * NO * 4 + (size_t)BATCH * NN * NK * 4);
        dim3 grid(LNBLK, BATCH / LBB);
        const int rblocks = BATCH * NK * NO / 256;
        legacy_pass<0><<<grid, LTHREADS, 0, stream>>>(xg, Wg, nullptr, logits, partial);
        legacy_reduce<<<rblocks, 256, 0, stream>>>(partial, outvL);
        legacy_pass<1><<<grid, LTHREADS, 0, stream>>>(xg, Wg, outvL, logits, partial);
        legacy_reduce<<<rblocks, 256, 0, stream>>>(partial, outvL);
        legacy_pass<2><<<grid, LTHREADS, 0, stream>>>(xg, Wg, outvL, logits, partial);
        legacy_reduce<<<rblocks, 256, 0, stream>>>(partial, outp);
    }
}